// Round 9
// baseline (236.545 us; speedup 1.0000x reference)
//
#include <hip/hip_runtime.h>

typedef unsigned short u16;

#define NGRAPH 16
#define SEQ    1024
#define DIM    128
#define NHEAD  2
#define HDIM   64
#define KPOS   20
#define NTOT   (NGRAPH*SEQ)     // 16384
#define QKVD   (3*DIM)          // 384

// ---------- bf16 helpers ----------------------------------------------------
__device__ __forceinline__ float bf2f(u16 u) {
    return __uint_as_float(((unsigned int)u) << 16);
}
__device__ __forceinline__ u16 f2bf(float f) {
    unsigned int u = __float_as_uint(f);
    u += 0x7fffu + ((u >> 16) & 1u);   // RNE
    return (u16)(u >> 16);
}
__device__ __forceinline__ float ld1(const void* p, int fbf, size_t i) {
    return fbf ? bf2f(((const u16*)p)[i]) : ((const float*)p)[i];
}
// 8 contiguous weights -> packed bf16x8 (as float4 bit pattern)
__device__ __forceinline__ float4 ldw8(const void* W, int fbf, size_t i) {
    if (fbf) return *(const float4*)((const u16*)W + i);
    const float* q = (const float*)W + i;
    float4 a = *(const float4*)q, b = *(const float4*)(q + 4);
    float4 r;
    u16* d = (u16*)&r;
    d[0]=f2bf(a.x); d[1]=f2bf(a.y); d[2]=f2bf(a.z); d[3]=f2bf(a.w);
    d[4]=f2bf(b.x); d[5]=f2bf(b.y); d[6]=f2bf(b.z); d[7]=f2bf(b.w);
    return r;
}

// ---------- K0: dtype detection --------------------------------------------
__global__ void detect_kernel(const u16* __restrict__ x, int* __restrict__ flag) {
    if (threadIdx.x == 0 && blockIdx.x == 0) {
        int ok = 1;
        for (int i = 0; i < 256; i += 2) {
            unsigned e = (x[i] >> 7) & 0xFF;
            if (e < 60u || e > 180u) ok = 0;
        }
        *flag = ok;
    }
}

typedef __attribute__((ext_vector_type(8))) short bf16x8;
typedef __attribute__((ext_vector_type(4))) float f32x4;

// ---------- K1: fused pe + qkv ---------------------------------------------
// Block 256 = 4 waves, 64 rows. Stage pe weights, compute h0 tile into LDS
// (and d_out slots for residual), then qkv = h0 @ in_w^T in 3 x 128-col
// chunks streamed through one LDS W buffer with reg prefetch.
__global__ __launch_bounds__(256)
void peqkv_kernel(const void* __restrict__ x, const void* __restrict__ pos,
                  const void* __restrict__ pe_w, const void* __restrict__ pe_b,
                  const void* __restrict__ in_w, const void* __restrict__ in_b,
                  u16* __restrict__ h0out, u16* __restrict__ qkv,
                  int arow0, int qrow0, const int* __restrict__ flag) {
    int fbf = *flag;
    int rs  = fbf ? 128 : 256;
    __shared__ u16   Wsh[128][136];    // 34.8 KB
    __shared__ u16   h0sh[64][136];    // 17.4 KB
    __shared__ float pwsh[DIM][KPOS + 1];   // 10.8 KB
    __shared__ float possh[64][KPOS + 1];   //  5.4 KB
    int t = threadIdx.x;
    int w = t >> 6, lane = t & 63, l16 = lane & 15, quad = lane >> 4;
    int n0 = blockIdx.x * 64;
    // prefetch W chunk 0 (in_w rows 0..127)
    float4 wR[8];
#pragma unroll
    for (int i = 0; i < 8; ++i) {
        int idx = t + i * 256;
        int m = idx >> 4, k8 = (idx & 15) * 8;
        wR[i] = ldw8(in_w, fbf, (size_t)m * DIM + k8);
    }
    // stage pe_w (128x20) and pos tile (64x20) as f32
    for (int i = t; i < DIM * KPOS; i += 256)
        pwsh[i / KPOS][i % KPOS] = ld1(pe_w, fbf, i);
    for (int i = t; i < 64 * KPOS; i += 256)
        possh[i / KPOS][i % KPOS] =
            ld1(pos, fbf, (size_t)(arow0 + n0 + i / KPOS) * KPOS + i % KPOS);
    __syncthreads();
    // pe compute: thread covers col d = t&127, rows rhalf*32..+32
    {
        int d = t & 127, rhalf = t >> 7;
        float pb = ld1(pe_b, fbf, d);
#pragma unroll 4
        for (int i = 0; i < 32; ++i) {
            int r = rhalf * 32 + i;
            float acc = 0.f;
#pragma unroll
            for (int k = 0; k < KPOS; ++k) acc += possh[r][k] * pwsh[d][k];
            float h = ld1(x, fbf, (size_t)(arow0 + n0 + r) * DIM + d) + acc + pb;
            u16 hb = f2bf(h);
            h0sh[r][d] = hb;
            h0out[(size_t)(arow0 + n0 + r) * rs + d] = hb;
        }
    }
    __syncthreads();
    // A fragments from h0sh
    bf16x8 af[4];
#pragma unroll
    for (int kk = 0; kk < 4; ++kk)
        af[kk] = *(const bf16x8*)&h0sh[w * 16 + l16][kk * 32 + quad * 8];
    // 3 chunks of 128 qkv cols
#pragma unroll 1
    for (int c = 0; c < 3; ++c) {
#pragma unroll
        for (int i = 0; i < 8; ++i) {
            int idx = t + i * 256;
            *(float4*)&Wsh[idx >> 4][(idx & 15) * 8] = wR[i];
        }
        __syncthreads();
        if (c < 2) {
#pragma unroll
            for (int i = 0; i < 8; ++i) {
                int idx = t + i * 256;
                int m = idx >> 4, k8 = (idx & 15) * 8;
                wR[i] = ldw8(in_w, fbf, (size_t)((c + 1) * 128 + m) * DIM + k8);
            }
        }
        f32x4 acc[8] = {};
#pragma unroll
        for (int kk = 0; kk < 4; ++kk) {
#pragma unroll
            for (int s = 0; s < 8; ++s) {
                bf16x8 bf = *(const bf16x8*)&Wsh[s * 16 + l16][kk * 32 + quad * 8];
                acc[s] = __builtin_amdgcn_mfma_f32_16x16x32_bf16(af[kk], bf, acc[s], 0, 0, 0);
            }
        }
#pragma unroll
        for (int s = 0; s < 8; ++s) {
            float bb = ld1(in_b, fbf, c * 128 + s * 16 + l16);
#pragma unroll
            for (int r = 0; r < 4; ++r) {
                int lr = w * 16 + quad * 4 + r;
                qkv[(size_t)(qrow0 + n0 + lr) * QKVD + c * 128 + s * 16 + l16] =
                    f2bf(acc[s][r] + bb);
            }
        }
        if (c < 2) __syncthreads();
    }
}

// ---------- K2: flash attention, MFMA bf16, 128-key tiles ------------------
// R7 staging shape (Qsh staged, single K/V buffer, reg prefetch, 2 barriers
// per tile) but 8 iterations of 128 keys instead of 16 x 64.
__global__ __launch_bounds__(256)
void attn_kernel(const u16* __restrict__ qkv, u16* __restrict__ ctx) {
    __shared__ u16 Qsh[64][72];      //  9.2 KB
    __shared__ u16 Ksh[128][72];     // 18.4 KB  [key][d]
    __shared__ u16 VshT[64][136];    // 17.4 KB  [d][key]
    __shared__ u16 Psh[64][136];     // 17.4 KB  [q][key]
    int t    = threadIdx.x;
    int w    = t >> 6;
    int lane = t & 63;
    int l16  = lane & 15;
    int quad = lane >> 4;
    int L = blockIdx.x;
    int ngh = gridDim.x >> 4;
    int qt, gh;
    if (ngh >= 8) {           // XCD swizzle: gh%8 == L%8
        int g8 = L & 7; int rest = L >> 3;
        qt = rest & 15; gh = (rest >> 4) * 8 + g8;
    } else {
        qt = L & 15; gh = L >> 4;
    }
    int b = gh >> 1, h = gh & 1;

    // stage Q tile
#pragma unroll
    for (int i = 0; i < 2; ++i) {
        int idx = t + i * 256;
        int r = idx >> 3, d8 = (idx & 7) * 8;
        size_t n = (size_t)b * SEQ + qt * 64 + r;
        *(float4*)&Qsh[r][d8] = *(const float4*)&qkv[n * QKVD + h * HDIM + d8];
    }
    // prefetch K/V tile 0 (128 keys)
    int kr = t >> 3, kd8 = (t & 7) * 8;       // K rows kr, kr+32, kr+64, kr+96
    int vk = t & 127, vh = t >> 7;            // V key, d-half
    float4 kR[4], vR[4];
    {
        size_t nk = (size_t)b * SEQ + kr;
#pragma unroll
        for (int i = 0; i < 4; ++i)
            kR[i] = *(const float4*)&qkv[(nk + i * 32) * QKVD + DIM + h * HDIM + kd8];
        size_t nv = (size_t)b * SEQ + vk;
#pragma unroll
        for (int i = 0; i < 4; ++i)
            vR[i] = *(const float4*)&qkv[nv * QKVD + 2 * DIM + h * HDIM + vh * 32 + i * 8];
    }
    __syncthreads();
    bf16x8 qa0 = *(const bf16x8*)&Qsh[w * 16 + l16][quad * 8];
    bf16x8 qa1 = *(const bf16x8*)&Qsh[w * 16 + l16][32 + quad * 8];

    f32x4 o[4] = {};
    float mrow[4] = {-1e30f, -1e30f, -1e30f, -1e30f};
    float lrow[4] = {};
    const float SCL = 0.125f * 1.44269504f;   // 1/sqrt(64) * log2(e)

#pragma unroll 1
    for (int kt = 0; kt < SEQ / 128; ++kt) {
        // regs -> LDS
#pragma unroll
        for (int i = 0; i < 4; ++i)
            *(float4*)&Ksh[kr + i * 32][kd8] = kR[i];
#pragma unroll
        for (int i = 0; i < 4; ++i) {
            const u16* pv = (const u16*)&vR[i];
#pragma unroll
            for (int j = 0; j < 8; ++j) VshT[vh * 32 + i * 8 + j][vk] = pv[j];
        }
        __syncthreads();
        if (kt + 1 < SEQ / 128) {   // prefetch next 128-key tile
            size_t nk = (size_t)b * SEQ + (kt + 1) * 128 + kr;
#pragma unroll
            for (int i = 0; i < 4; ++i)
                kR[i] = *(const float4*)&qkv[(nk + i * 32) * QKVD + DIM + h * HDIM + kd8];
            size_t nv = (size_t)b * SEQ + (kt + 1) * 128 + vk;
#pragma unroll
            for (int i = 0; i < 4; ++i)
                vR[i] = *(const float4*)&qkv[nv * QKVD + 2 * DIM + h * HDIM + vh * 32 + i * 8];
        }
        // S = Q K^T over 8 key-subtiles
        float sc[8][4];
#pragma unroll
        for (int c = 0; c < 8; ++c) {
            bf16x8 kb0 = *(const bf16x8*)&Ksh[c * 16 + l16][quad * 8];
            bf16x8 kb1 = *(const bf16x8*)&Ksh[c * 16 + l16][32 + quad * 8];
            f32x4 s = {};
            s = __builtin_amdgcn_mfma_f32_16x16x32_bf16(qa0, kb0, s, 0, 0, 0);
            s = __builtin_amdgcn_mfma_f32_16x16x32_bf16(qa1, kb1, s, 0, 0, 0);
#pragma unroll
            for (int r = 0; r < 4; ++r) sc[c][r] = s[r] * SCL;   // log2-domain
        }
        // online softmax per row
        float alpha[4];
#pragma unroll
        for (int r = 0; r < 4; ++r) {
            float mx = sc[0][r];
#pragma unroll
            for (int c = 1; c < 8; ++c) mx = fmaxf(mx, sc[c][r]);
#pragma unroll
            for (int off = 1; off < 16; off <<= 1)
                mx = fmaxf(mx, __shfl_xor(mx, off, 64));
            float mnew = fmaxf(mrow[r], mx);
            alpha[r] = exp2f(mrow[r] - mnew);
            mrow[r] = mnew;
            float sum = 0.f;
#pragma unroll
            for (int c = 0; c < 8; ++c) {
                float p = exp2f(sc[c][r] - mnew);
                sc[c][r] = p;
                sum += p;
            }
#pragma unroll
            for (int off = 1; off < 16; off <<= 1)
                sum += __shfl_xor(sum, off, 64);
            lrow[r] = lrow[r] * alpha[r] + sum;
        }
        // P -> LDS (wave-private band), rescale O
#pragma unroll
        for (int c = 0; c < 8; ++c)
#pragma unroll
            for (int r = 0; r < 4; ++r)
                Psh[w * 16 + quad * 4 + r][c * 16 + l16] = f2bf(sc[c][r]);
#pragma unroll
        for (int dt = 0; dt < 4; ++dt)
#pragma unroll
            for (int r = 0; r < 4; ++r) o[dt][r] *= alpha[r];
        // O += P V  (K-dim = 128 keys = 4 k32 chunks)
        bf16x8 pa[4];
#pragma unroll
        for (int kk = 0; kk < 4; ++kk)
            pa[kk] = *(const bf16x8*)&Psh[w * 16 + l16][kk * 32 + quad * 8];
#pragma unroll
        for (int dt = 0; dt < 4; ++dt) {
#pragma unroll
            for (int kk = 0; kk < 4; ++kk) {
                bf16x8 vb = *(const bf16x8*)&VshT[dt * 16 + l16][kk * 32 + quad * 8];
                o[dt] = __builtin_amdgcn_mfma_f32_16x16x32_bf16(pa[kk], vb, o[dt], 0, 0, 0);
            }
        }
        __syncthreads();
    }
#pragma unroll
    for (int r = 0; r < 4; ++r) {
        float inv = 1.f / lrow[r];
        size_t n = (size_t)b * SEQ + qt * 64 + w * 16 + quad * 4 + r;
#pragma unroll
        for (int dt = 0; dt < 4; ++dt)
            ctx[n * DIM + h * HDIM + dt * 16 + l16] = f2bf(o[dt][r] * inv);
    }
}

// ---------- K3: fused proj+LN1+FF+LN2 --------------------------------------
// Block 256 = 4 waves, 64 rows. sa = ctx@out_w^T + b + h0 -> LN1 -> h1 (LDS,
// wave-local) -> ff chunks (W1c/W2c streamed) -> +h1 -> LN2 -> final out.
__global__ __launch_bounds__(256)
void projff_kernel(const u16* __restrict__ ctx, const void* __restrict__ oW,
                   const void* __restrict__ oB, const void* __restrict__ W1,
                   const void* __restrict__ b1, const void* __restrict__ W2,
                   const void* __restrict__ b2, const void* __restrict__ g1,
                   const void* __restrict__ e1, const void* __restrict__ g2,
                   const void* __restrict__ e2, const u16* __restrict__ h01,
                   void* __restrict__ outp, int arow0, int qrow0,
                   const int* __restrict__ flag) {
    int fbf = *flag;
    int rs  = fbf ? 128 : 256;
    __shared__ u16 Wsh[128][136];    // 34.8 KB
    __shared__ u16 h1sh[64][136];    // 17.4 KB
    __shared__ u16 f1sh[64][136];    // 17.4 KB
    int t = threadIdx.x;
    int w = t >> 6, lane = t & 63, l16 = lane & 15, quad = lane >> 4;
    int n0 = blockIdx.x * 64;
    // ctx A-fragments from global
    bf16x8 af[4];
#pragma unroll
    for (int kk = 0; kk < 4; ++kk)
        af[kk] = *(const bf16x8*)&ctx[(size_t)(qrow0 + n0 + w * 16 + l16) * DIM
                                      + kk * 32 + quad * 8];
    // stage out_w (128x128)
    float4 wR[8];
#pragma unroll
    for (int i = 0; i < 8; ++i) {
        int idx = t + i * 256;
        int m = idx >> 4, k8 = (idx & 15) * 8;
        wR[i] = ldw8(oW, fbf, (size_t)m * DIM + k8);
    }
#pragma unroll
    for (int i = 0; i < 8; ++i) {
        int idx = t + i * 256;
        *(float4*)&Wsh[idx >> 4][(idx & 15) * 8] = wR[i];
    }
    __syncthreads();
    // prefetch W1 chunk 0
#pragma unroll
    for (int i = 0; i < 8; ++i) {
        int idx = t + i * 256;
        int m = idx >> 4, k8 = (idx & 15) * 8;
        wR[i] = ldw8(W1, fbf, (size_t)m * DIM + k8);
    }
    // proj MFMA
    f32x4 acc[8] = {};
#pragma unroll
    for (int kk = 0; kk < 4; ++kk) {
#pragma unroll
        for (int s = 0; s < 8; ++s) {
            bf16x8 bf = *(const bf16x8*)&Wsh[s * 16 + l16][kk * 32 + quad * 8];
            acc[s] = __builtin_amdgcn_mfma_f32_16x16x32_bf16(af[kk], bf, acc[s], 0, 0, 0);
        }
    }
    // sa + bias + h0 resid -> LN1 -> h1sh (wave-local rows)
#pragma unroll
    for (int r = 0; r < 4; ++r) {
        size_t rg = (size_t)(arow0 + n0 + w * 16 + quad * 4 + r);
        float v[8];
#pragma unroll
        for (int s = 0; s < 8; ++s)
            v[s] = acc[s][r] + ld1(oB, fbf, s * 16 + l16)
                 + bf2f(h01[rg * rs + s * 16 + l16]);
        float sm = 0.f, sq = 0.f;
#pragma unroll
        for (int s = 0; s < 8; ++s) { sm += v[s]; sq += v[s] * v[s]; }
#pragma unroll
        for (int off = 1; off < 16; off <<= 1) {
            sm += __shfl_xor(sm, off, 64);
            sq += __shfl_xor(sq, off, 64);
        }
        float mu  = sm * (1.f / DIM);
        float var = fmaxf(sq * (1.f / DIM) - mu * mu, 0.f);
        float rsq = rsqrtf(var + 1e-5f);
#pragma unroll
        for (int s = 0; s < 8; ++s)
            h1sh[w * 16 + quad * 4 + r][s * 16 + l16] =
                f2bf((v[s] - mu) * rsq * ld1(g1, fbf, s * 16 + l16)
                     + ld1(e1, fbf, s * 16 + l16));
    }
    __syncthreads();   // Wsh reuse
    // h1 A-fragments (wave-local band)
    bf16x8 hf[4];
#pragma unroll
    for (int kk = 0; kk < 4; ++kk)
        hf[kk] = *(const bf16x8*)&h1sh[w * 16 + l16][kk * 32 + quad * 8];
    f32x4 acc2[8] = {};
#pragma unroll 1
    for (int c = 0; c < 4; ++c) {
        // W1c regs -> LDS
#pragma unroll
        for (int i = 0; i < 8; ++i) {
            int idx = t + i * 256;
            *(float4*)&Wsh[idx >> 4][(idx & 15) * 8] = wR[i];
        }
        __syncthreads();
        // prefetch W2c
#pragma unroll
        for (int i = 0; i < 8; ++i) {
            int idx = t + i * 256;
            int m = idx >> 4, k8 = (idx & 15) * 8;
            wR[i] = ldw8(W2, fbf, (size_t)m * 512 + c * 128 + k8);
        }
        // MFMA1: f1c = h1 @ W1c^T
        f32x4 acc1[8] = {};
#pragma unroll
        for (int kk = 0; kk < 4; ++kk) {
#pragma unroll
            for (int s = 0; s < 8; ++s) {
                bf16x8 bf = *(const bf16x8*)&Wsh[s * 16 + l16][kk * 32 + quad * 8];
                acc1[s] = __builtin_amdgcn_mfma_f32_16x16x32_bf16(hf[kk], bf, acc1[s], 0, 0, 0);
            }
        }
#pragma unroll
        for (int s = 0; s < 8; ++s) {
            float bb1 = ld1(b1, fbf, c * 128 + s * 16 + l16);
#pragma unroll
            for (int r = 0; r < 4; ++r)
                f1sh[w * 16 + quad * 4 + r][s * 16 + l16] =
                    f2bf(fmaxf(acc1[s][r] + bb1, 0.f));
        }
        __syncthreads();   // all waves done with Wsh (W1c)
        // W2c regs -> LDS
#pragma unroll
        for (int i = 0; i < 8; ++i) {
            int idx = t + i * 256;
            *(float4*)&Wsh[idx >> 4][(idx & 15) * 8] = wR[i];
        }
        __syncthreads();
        // prefetch W1 chunk c+1
        if (c < 3) {
#pragma unroll
            for (int i = 0; i < 8; ++i) {
                int idx = t + i * 256;
                int m = idx >> 4, k8 = (idx & 15) * 8;
                wR[i] = ldw8(W1, fbf, (size_t)((c + 1) * 128 + m) * DIM + k8);
            }
        }
        // MFMA2: acc2 += f1c @ W2c^T
#pragma unroll
        for (int kk = 0; kk < 4; ++kk) {
            bf16x8 pf = *(const bf16x8*)&f1sh[w * 16 + l16][kk * 32 + quad * 8];
#pragma unroll
            for (int s = 0; s < 8; ++s) {
                bf16x8 bf = *(const bf16x8*)&Wsh[s * 16 + l16][kk * 32 + quad * 8];
                acc2[s] = __builtin_amdgcn_mfma_f32_16x16x32_bf16(pf, bf, acc2[s], 0, 0, 0);
            }
        }
        if (c < 3) __syncthreads();
    }
    // epilogue: +b2 +h1 resid -> LN2 -> final out
#pragma unroll
    for (int r = 0; r < 4; ++r) {
        size_t rg = (size_t)(arow0 + n0 + w * 16 + quad * 4 + r);
        float v[8];
#pragma unroll
        for (int s = 0; s < 8; ++s)
            v[s] = acc2[s][r] + ld1(b2, fbf, s * 16 + l16)
                 + bf2f(h1sh[w * 16 + quad * 4 + r][s * 16 + l16]);
        float sm = 0.f, sq = 0.f;
#pragma unroll
        for (int s = 0; s < 8; ++s) { sm += v[s]; sq += v[s] * v[s]; }
#pragma unroll
        for (int off = 1; off < 16; off <<= 1) {
            sm += __shfl_xor(sm, off, 64);
            sq += __shfl_xor(sq, off, 64);
        }
        float mu  = sm * (1.f / DIM);
        float var = fmaxf(sq * (1.f / DIM) - mu * mu, 0.f);
        float rsq = rsqrtf(var + 1e-5f);
        if (fbf) {
            u16* o = (u16*)outp;
#pragma unroll
            for (int s = 0; s < 8; ++s)
                o[rg * 128 + s * 16 + l16] =
                    f2bf((v[s] - mu) * rsq * ld1(g2, fbf, s * 16 + l16)
                         + ld1(e2, fbf, s * 16 + l16));
        } else {
            float* o = (float*)outp;
#pragma unroll
            for (int s = 0; s < 8; ++s)
                o[rg * 128 + s * 16 + l16] =
                    (v[s] - mu) * rsq * ld1(g2, fbf, s * 16 + l16)
                    + ld1(e2, fbf, s * 16 + l16);
        }
    }
}

// ---------------------------------------------------------------------------
extern "C" void kernel_launch(void* const* d_in, const int* in_sizes, int n_in,
                              void* d_out, int out_size, void* d_ws, size_t ws_size,
                              hipStream_t stream) {
    const void* x     = d_in[0];
    const void* pos   = d_in[1];
    const void* pe_w  = d_in[2];
    const void* pe_b  = d_in[3];
    const void* in_w  = d_in[4];
    const void* in_b  = d_in[5];
    const void* out_w = d_in[6];
    const void* out_b = d_in[7];
    const void* ln1_g = d_in[8];
    const void* ln1_b = d_in[9];
    const void* ln2_g = d_in[10];
    const void* ln2_b = d_in[11];
    const void* ff1_w = d_in[12];
    const void* ff1_b = d_in[13];
    const void* ff2_w = d_in[14];
    const void* ff2_b = d_in[15];

    char* wsb  = (char*)d_ws;
    int*  flag = (int*)(wsb + ((ws_size - 4) & ~(size_t)3));
    u16*  h01  = (u16*)d_out;   // h0 (residual), bf16 in dtype-dependent slots
    const size_t MB = 1024 * 1024;

    detect_kernel<<<1, 1, 0, stream>>>((const u16*)x, flag);

    if (ws_size >= 17 * MB) {
        // batched: qkv[0,12M), ctx[12M,16M)
        u16* qkv = (u16*)wsb;
        u16* ctx = (u16*)(wsb + 12 * MB);
        peqkv_kernel<<<NTOT / 64, 256, 0, stream>>>(
            x, pos, pe_w, pe_b, in_w, in_b, h01, qkv, 0, 0, flag);
        attn_kernel<<<NGRAPH * NHEAD * 16, 256, 0, stream>>>(qkv, ctx);
        projff_kernel<<<NTOT / 64, 256, 0, stream>>>(
            ctx, out_w, out_b, ff1_w, ff1_b, ff2_w, ff2_b,
            ln1_g, ln1_b, ln2_g, ln2_b, h01, d_out, 0, 0, flag);
    } else {
        // per-graph: qkv_g[0,768K), ctx_g[768K,1M)
        u16* qkv_g = (u16*)wsb;
        u16* ctx_g = (u16*)(wsb + 768 * 1024);
        for (int g = 0; g < NGRAPH; ++g) {
            int row0 = g * SEQ;
            peqkv_kernel<<<SEQ / 64, 256, 0, stream>>>(
                x, pos, pe_w, pe_b, in_w, in_b, h01, qkv_g, row0, 0, flag);
            attn_kernel<<<NHEAD * 16, 256, 0, stream>>>(qkv_g, ctx_g);
            projff_kernel<<<SEQ / 64, 256, 0, stream>>>(
                ctx_g, out_w, out_b, ff1_w, ff1_b, ff2_w, ff2_b,
                ln1_g, ln1_b, ln2_g, ln2_b, h01, d_out, row0, 0, flag);
        }
    }
}